// Round 17
// baseline (24.105 us; speedup 1.0000x reference)
//
#include <hip/hip_runtime.h>

// HistByProfMultiChannel: x (16,128,56,56) f32, hist_edges (128,10) f32,
// out (16,128,11) f32.
//
// R17: R16 body, 2x block split (4096 blocks, 8 px/thread) + atomicAdd merge.
//  - Device-level ledger: VALU issue floor ~6.9us, mem ~2-4us, launch ~2 =>
//    ~9-10us floor vs 16 measured. The gap is per-block serial depth
//    (16px load-drain + compute tail) and ramp. Halving per-thread work
//    halves the critical path; 2 blocks/channel-row merge via atomicAdd
//    from a memset-0 base. Exactly 2 contributors per cell: a+b == b+a in
//    IEEE, so the sum is bit-deterministic regardless of arrival order.
//  - Proven chain math untouched (absmax 0.5): biased geometric chain
//    (2^88), anchors at bins 0/1/6, 6 trans/px, v2f math.
//  - hipMemsetAsync(d_out) on-stream before the kernel (graph-capture-safe;
//    the harness itself enqueues hipMemsetAsync during reset).

#define NE 10
#define NBINS 11
#define HW 3136
#define HWH 1568      // HW/2 per block
#define HWH4 392      // float4s per block
#define NCH 128
#define BIAS 88.0f

typedef float v2f __attribute__((ext_vector_type(2)));

__device__ __forceinline__ float rfl(float xv) {
    return __int_as_float(__builtin_amdgcn_readfirstlane(__float_as_int(xv)));
}
__device__ __forceinline__ v2f exp2v(v2f a) {
    v2f r;
    r.x = __builtin_amdgcn_exp2f(a.x);
    r.y = __builtin_amdgcn_exp2f(a.y);
    return r;
}

struct UniCoef {
    float A, B0, C0, B1, C1, B6, C6, dB, dC, rho, rho2, HC, sB, sC;
};

// Process two pixels (one v2f) through the biased chain.
__device__ __forceinline__ void chain2(v2f v, const UniCoef& u, v2f* acc2) {
    v2f vg = __builtin_elementwise_min(v, (v2f){u.HC, u.HC});
    v2f q  = vg * vg;
    v2f t0 = u.A * q + (u.B0 * vg + u.C0);
    v2f t1 = u.A * q + (u.B1 * vg + u.C1);
    v2f t6 = u.A * q + (u.B6 * vg + u.C6);
    v2f rr = exp2v(u.dB * vg + (v2f){u.dC, u.dC});
    acc2[0] += exp2v(t0);
    v2f g = exp2v(t1);
    acc2[1] += g;
    g *= rr; acc2[2] += g; rr *= u.rho;
    g *= rr; acc2[3] += g; rr *= u.rho;
    g *= rr; acc2[4] += g; rr *= u.rho;
    g *= rr; acc2[5] += g; rr *= u.rho2;   // rr: r4 -> r6
    v2f h = exp2v(t6);
    acc2[6] += h;
    h *= rr; acc2[7] += h; rr *= u.rho;
    h *= rr; acc2[8] += h; rr *= u.rho;
    h *= rr; acc2[9] += h;
    // sigmoid: s = sB*v + sC (UNclamped v); sigma = 1/(1+2^s)
    v2f sd = exp2v(u.sB * v + (v2f){u.sC, u.sC});
    v2f sig;
    sig.x = __builtin_amdgcn_rcpf(1.0f + sd.x);
    sig.y = __builtin_amdgcn_rcpf(1.0f + sd.y);
    acc2[10] += sig;
}

__global__ __launch_bounds__(256)
void hist_kernel(const float* __restrict__ x,
                 const float* __restrict__ edges,
                 float* __restrict__ out) {
    const int blk  = blockIdx.x;         // 2 blocks per (bt,c)
    const int bc   = blk >> 1;
    const int half = blk & 1;
    const int c    = bc & (NCH - 1);
    const int tid  = threadIdx.x;

    const float LOG2E = 1.4426950408889634f;

    float e[NE];
    #pragma unroll
    for (int j = 0; j < NE; ++j) e[j] = rfl(edges[c * NE + j]);

    // This block's half-row: 392 float4s. Chunk 0 = all 256 lanes;
    // chunk 1 = lanes 0..135 (sentinel elsewhere).
    const float4* xp = (const float4*)(x + (size_t)bc * HW + (size_t)half * HWH);
    const bool t2 = tid < (HWH4 - 256);   // 136 lanes
    float4 p0 = xp[tid];
    float4 p1 = xp[t2 ? 256 + tid : tid];

    v2f acc2[NBINS];
    #pragma unroll
    for (int j = 0; j < NBINS; ++j) acc2[j] = (v2f){0.f, 0.f};

    const float D = e[1] - e[0];
    bool uniform = (D > 1e-6f);
    #pragma unroll
    for (int j = 1; j < NE - 1; ++j)
        uniform = uniform && (fabsf((e[j + 1] - e[j]) - D) <= 1e-4f * fabsf(D));

    const float sB = rfl(-20.0f * LOG2E);
    const float sC = rfl(20.0f * LOG2E * e[NE - 1]);

    if (uniform) {
        UniCoef u;
        const float sg  = -D * (1.0f / 3.0f) + 1e-6f;
        const float A   = rfl(-0.5f * LOG2E / (sg * sg));   // < 0 (log2 space)
        const float mu1 = e[0] + 0.5f * D;
        const float mu6 = e[0] + 5.5f * D;
        u.A  = A;
        u.B0 = rfl(-2.0f * A * e[0]); u.C0 = rfl(A * e[0] * e[0] + BIAS);
        u.B1 = rfl(-2.0f * A * mu1);  u.C1 = rfl(A * mu1 * mu1 + BIAS);
        u.B6 = rfl(-2.0f * A * mu6);  u.C6 = rfl(A * mu6 * mu6 + BIAS);
        u.dB = rfl(-2.0f * A * D);
        u.dC = rfl(A * D * (mu1 + mu1 + D));
        u.rho  = rfl(__builtin_amdgcn_exp2f(2.0f * A * D * D));   // < 1
        u.rho2 = rfl(u.rho * u.rho);
        u.HC = rfl((126.0f - u.dC) / u.dB);           // keep r finite
        u.sB = sB; u.sC = sC;

        const float q0 = t2 ? p1.x : -1e18f;
        const float q1 = t2 ? p1.y : -1e18f;
        const float q2 = t2 ? p1.z : -1e18f;
        const float q3 = t2 ? p1.w : -1e18f;

        chain2((v2f){p0.x, p0.y}, u, acc2);
        chain2((v2f){p0.z, p0.w}, u, acc2);
        chain2((v2f){q0, q1}, u, acc2);
        chain2((v2f){q2, q3}, u, acc2);
    } else {
        // General path: direct per-bin quadratic exp2 (unbiased).
        float As[NE], Bs[NE], Cs[NE];
        {
            float mu = e[0];
            float s2 = (e[0] - e[1]) * (1.0f / 3.0f) + 1e-6f;
            float kk = -0.5f * LOG2E / (s2 * s2);
            As[0] = rfl(kk); Bs[0] = rfl(-2.0f * kk * mu); Cs[0] = rfl(kk * mu * mu);
        }
        #pragma unroll
        for (int j = 1; j < NE; ++j) {
            float mu = (e[j - 1] + e[j]) * 0.5f;
            float s2 = (e[j - 1] - e[j]) * (1.0f / 3.0f) + 1e-6f;
            float kk = -0.5f * LOG2E / (s2 * s2);
            As[j] = rfl(kk); Bs[j] = rfl(-2.0f * kk * mu); Cs[j] = rfl(kk * mu * mu);
        }
        float vsg[8] = {p0.x, p0.y, p0.z, p0.w,
                        t2 ? p1.x : -1e18f, t2 ? p1.y : -1e18f,
                        t2 ? p1.z : -1e18f, t2 ? p1.w : -1e18f};
        #pragma unroll
        for (int k = 0; k < 8; ++k) {
            float v = vsg[k], v2 = v * v;
            #pragma unroll
            for (int j = 0; j < NE; ++j) {
                float arg = fmaf(As[j], v2, fmaf(Bs[j], v, Cs[j]));
                acc2[j].x += __builtin_amdgcn_exp2f(arg);
            }
            float den = 1.0f + __builtin_amdgcn_exp2f(fmaf(sB, v, sC));
            acc2[10].x += __builtin_amdgcn_rcpf(den);
        }
    }

    float acc[NBINS];
    #pragma unroll
    for (int j = 0; j < NBINS; ++j) acc[j] = acc2[j].x + acc2[j].y;

    // Wave (64-lane) reduce each accumulator.
    #pragma unroll
    for (int j = 0; j < NBINS; ++j) {
        float a = acc[j];
        #pragma unroll
        for (int off = 32; off > 0; off >>= 1)
            a += __shfl_down(a, off, 64);
        acc[j] = a;
    }

    // Cross-wave reduce via LDS (4 waves x 11 bins), then atomic merge of
    // the two half-row blocks (exactly 2 contributors -> a+b == b+a,
    // bit-deterministic from the memset-0 base).
    __shared__ float red[4][NBINS];
    const int wave = tid >> 6;
    const int lane = tid & 63;
    if (lane == 0) {
        #pragma unroll
        for (int j = 0; j < NBINS; ++j) red[wave][j] = acc[j];
    }
    __syncthreads();
    if (tid < NBINS) {
        float s = red[0][tid] + red[1][tid] + red[2][tid] + red[3][tid];
        const float unb = (uniform && tid < NE) ? 0x1p-88f : 1.0f;
        atomicAdd(&out[(size_t)bc * NBINS + tid], s * unb);
    }
}

extern "C" void kernel_launch(void* const* d_in, const int* in_sizes, int n_in,
                              void* d_out, int out_size, void* d_ws, size_t ws_size,
                              hipStream_t stream) {
    const float* x     = (const float*)d_in[0];
    const float* edges = (const float*)d_in[1];
    float* out         = (float*)d_out;
    // Zero the output (atomic merge base). Async memset is capture-safe.
    hipMemsetAsync(out, 0, (size_t)out_size * sizeof(float), stream);
    hist_kernel<<<dim3(16 * NCH * 2), dim3(256), 0, stream>>>(x, edges, out);
}

// Round 18
// 16.176 us; speedup vs baseline: 1.4901x; 1.4901x over previous
//
#include <hip/hip_runtime.h>

// HistByProfMultiChannel: x (16,128,56,56) f32, hist_edges (128,10) f32,
// out (16,128,11) f32.
//
// R18 = R16/R10 restored verbatim (best known: 15.97us, absmax 0.5).
// Converged cost model (fits all 17 rounds):
//   wall = T_fixed (~7.6us dispatch overhead + unoverlapped stream-in)
//        + T_compute (~8.1us; ~304 issue-cy per pixel-pair, VALUBusy 86%).
// - Trans-shaving (R7/R8/R13/R14), poly-exp2 (R11/R12), packed-f32 asm
//   (R15), compaction (R5), micro-hist (R3/R4), block-split+memset (R17)
//   all landed neutral-to-worse: CDNA4 fp32 is SIMD-32 scalar-rate (no
//   pk-f32 issue gain) and trans<->VALU trades stay ~300 cy/pair.
// - 2048 blocks x 4 waves = 8192 waves = exactly device capacity: single
//   full residency generation; splitting adds dispatches (~5-8us each).
// Kernel detail: biased geometric chain (2^88) -- Gaussians as
// exp2(A v^2+Bv+C+88) anchored at bins 0/1/6, interior bins by the
// v-dependent ratio r = exp2(dB v + dC) with rho = 2^{2AD^2} updates;
// 6 trans/px; acc[0..9] unbiased by 2^-88 after the block reduction.

#define NE 10
#define NBINS 11
#define HW 3136
#define HW4 784
#define NCH 128
#define BIAS 88.0f

typedef float v2f __attribute__((ext_vector_type(2)));

__device__ __forceinline__ float rfl(float xv) {
    return __int_as_float(__builtin_amdgcn_readfirstlane(__float_as_int(xv)));
}
__device__ __forceinline__ v2f exp2v(v2f a) {
    v2f r;
    r.x = __builtin_amdgcn_exp2f(a.x);
    r.y = __builtin_amdgcn_exp2f(a.y);
    return r;
}

struct UniCoef {
    float A, B0, C0, B1, C1, B6, C6, dB, dC, rho, rho2, HC, sB, sC;
};

// Process two pixels (one v2f) through the biased chain.
__device__ __forceinline__ void chain2(v2f v, const UniCoef& u, v2f* acc2) {
    v2f vg = __builtin_elementwise_min(v, (v2f){u.HC, u.HC});
    v2f q  = vg * vg;
    v2f t0 = u.A * q + (u.B0 * vg + u.C0);
    v2f t1 = u.A * q + (u.B1 * vg + u.C1);
    v2f t6 = u.A * q + (u.B6 * vg + u.C6);
    v2f rr = exp2v(u.dB * vg + (v2f){u.dC, u.dC});
    acc2[0] += exp2v(t0);
    v2f g = exp2v(t1);
    acc2[1] += g;
    g *= rr; acc2[2] += g; rr *= u.rho;
    g *= rr; acc2[3] += g; rr *= u.rho;
    g *= rr; acc2[4] += g; rr *= u.rho;
    g *= rr; acc2[5] += g; rr *= u.rho2;   // rr: r4 -> r6
    v2f h = exp2v(t6);
    acc2[6] += h;
    h *= rr; acc2[7] += h; rr *= u.rho;
    h *= rr; acc2[8] += h; rr *= u.rho;
    h *= rr; acc2[9] += h;
    // sigmoid: s = sB*v + sC (UNclamped v); sigma = 1/(1+2^s)
    v2f sd = exp2v(u.sB * v + (v2f){u.sC, u.sC});
    v2f sig;
    sig.x = __builtin_amdgcn_rcpf(1.0f + sd.x);
    sig.y = __builtin_amdgcn_rcpf(1.0f + sd.y);
    acc2[10] += sig;
}

__global__ __launch_bounds__(256)
void hist_kernel(const float* __restrict__ x,
                 const float* __restrict__ edges,
                 float* __restrict__ out) {
    const int bc  = blockIdx.x;          // bt*NCH + c
    const int c   = bc & (NCH - 1);
    const int tid = threadIdx.x;

    const float LOG2E = 1.4426950408889634f;

    float e[NE];
    #pragma unroll
    for (int j = 0; j < NE; ++j) e[j] = rfl(edges[c * NE + j]);

    // Issue all 4 chunk loads up front; each chunk's compute consumes only
    // its own registers so the compiler waits vmcnt(3/2/1/0) progressively.
    const float4* xp = (const float4*)(x + (size_t)bc * HW);
    float4 p0 = xp[tid];
    float4 p1 = xp[tid + 256];
    float4 p2 = xp[tid + 512];
    float4 p3;
    if (tid < (HW4 - 768)) p3 = xp[768 + tid];
    else { p3.x = p3.y = p3.z = p3.w = -1e18f; }   // sentinel -> all profiles 0

    v2f acc2[NBINS];
    #pragma unroll
    for (int j = 0; j < NBINS; ++j) acc2[j] = (v2f){0.f, 0.f};

    const float D = e[1] - e[0];
    bool uniform = (D > 1e-6f);
    #pragma unroll
    for (int j = 1; j < NE - 1; ++j)
        uniform = uniform && (fabsf((e[j + 1] - e[j]) - D) <= 1e-4f * fabsf(D));

    const float sB = rfl(-20.0f * LOG2E);
    const float sC = rfl(20.0f * LOG2E * e[NE - 1]);

    if (uniform) {
        UniCoef u;
        const float sg  = -D * (1.0f / 3.0f) + 1e-6f;
        const float A   = rfl(-0.5f * LOG2E / (sg * sg));   // < 0 (log2 space)
        const float mu1 = e[0] + 0.5f * D;
        const float mu6 = e[0] + 5.5f * D;
        u.A  = A;
        u.B0 = rfl(-2.0f * A * e[0]); u.C0 = rfl(A * e[0] * e[0] + BIAS);
        u.B1 = rfl(-2.0f * A * mu1);  u.C1 = rfl(A * mu1 * mu1 + BIAS);
        u.B6 = rfl(-2.0f * A * mu6);  u.C6 = rfl(A * mu6 * mu6 + BIAS);
        u.dB = rfl(-2.0f * A * D);
        u.dC = rfl(A * D * (mu1 + mu1 + D));
        u.rho  = rfl(__builtin_amdgcn_exp2f(2.0f * A * D * D));   // < 1
        u.rho2 = rfl(u.rho * u.rho);
        u.HC = rfl((126.0f - u.dC) / u.dB);           // keep r finite
        u.sB = sB; u.sC = sC;

        // chunk 0 (waits only its own load)
        chain2((v2f){p0.x, p0.y}, u, acc2);
        chain2((v2f){p0.z, p0.w}, u, acc2);
        // chunk 1
        chain2((v2f){p1.x, p1.y}, u, acc2);
        chain2((v2f){p1.z, p1.w}, u, acc2);
        // chunk 2
        chain2((v2f){p2.x, p2.y}, u, acc2);
        chain2((v2f){p2.z, p2.w}, u, acc2);
        // chunk 3
        chain2((v2f){p3.x, p3.y}, u, acc2);
        chain2((v2f){p3.z, p3.w}, u, acc2);
    } else {
        // General path: direct per-bin quadratic exp2 (unbiased).
        float As[NE], Bs[NE], Cs[NE];
        {
            float mu = e[0];
            float s2 = (e[0] - e[1]) * (1.0f / 3.0f) + 1e-6f;
            float kk = -0.5f * LOG2E / (s2 * s2);
            As[0] = rfl(kk); Bs[0] = rfl(-2.0f * kk * mu); Cs[0] = rfl(kk * mu * mu);
        }
        #pragma unroll
        for (int j = 1; j < NE; ++j) {
            float mu = (e[j - 1] + e[j]) * 0.5f;
            float s2 = (e[j - 1] - e[j]) * (1.0f / 3.0f) + 1e-6f;
            float kk = -0.5f * LOG2E / (s2 * s2);
            As[j] = rfl(kk); Bs[j] = rfl(-2.0f * kk * mu); Cs[j] = rfl(kk * mu * mu);
        }
        float vsg[16] = {p0.x,p0.y,p0.z,p0.w, p1.x,p1.y,p1.z,p1.w,
                         p2.x,p2.y,p2.z,p2.w, p3.x,p3.y,p3.z,p3.w};
        #pragma unroll
        for (int k = 0; k < 16; ++k) {
            float v = vsg[k], v2 = v * v;
            #pragma unroll
            for (int j = 0; j < NE; ++j) {
                float arg = fmaf(As[j], v2, fmaf(Bs[j], v, Cs[j]));
                acc2[j].x += __builtin_amdgcn_exp2f(arg);
            }
            float den = 1.0f + __builtin_amdgcn_exp2f(fmaf(sB, v, sC));
            acc2[10].x += __builtin_amdgcn_rcpf(den);
        }
    }

    float acc[NBINS];
    #pragma unroll
    for (int j = 0; j < NBINS; ++j) acc[j] = acc2[j].x + acc2[j].y;

    // Wave (64-lane) reduce each accumulator.
    #pragma unroll
    for (int j = 0; j < NBINS; ++j) {
        float a = acc[j];
        #pragma unroll
        for (int off = 32; off > 0; off >>= 1)
            a += __shfl_down(a, off, 64);
        acc[j] = a;
    }

    // Cross-wave reduce via LDS (4 waves x 11 bins).
    __shared__ float red[4][NBINS];
    const int wave = tid >> 6;
    const int lane = tid & 63;
    if (lane == 0) {
        #pragma unroll
        for (int j = 0; j < NBINS; ++j) red[wave][j] = acc[j];
    }
    __syncthreads();
    if (tid < NBINS) {
        float s = red[0][tid] + red[1][tid] + red[2][tid] + red[3][tid];
        // Unbias Gaussian bins (uniform path only); sigmoid bin unbiased.
        const float unb = (uniform && tid < NE) ? 0x1p-88f : 1.0f;
        out[(size_t)bc * NBINS + tid] = s * unb;
    }
}

extern "C" void kernel_launch(void* const* d_in, const int* in_sizes, int n_in,
                              void* d_out, int out_size, void* d_ws, size_t ws_size,
                              hipStream_t stream) {
    const float* x     = (const float*)d_in[0];
    const float* edges = (const float*)d_in[1];
    float* out         = (float*)d_out;
    hist_kernel<<<dim3(16 * NCH), dim3(256), 0, stream>>>(x, edges, out);
}